// Round 1
// baseline (184.613 us; speedup 1.0000x reference)
//
#include <hip/hip_runtime.h>
#include <hip/hip_bf16.h>
#include <math.h>

#define NPIX 2304
#define CCH  128
#define NH   4
#define HC   32
#define NCL  16
#define NBLK 72                          // pixel blocks of 32 for centers
#define KSPLIT 8
#define KEYS 288                         // NPIX / KSPLIT
#define NSTEP 9                          // KEYS / 32
// q pre-scale: log2(e)/sqrt(32)  (folds the exp->exp2 conversion into q)
#define QSCALE 0.25503489f

typedef __attribute__((ext_vector_type(8))) short short8;
typedef __attribute__((ext_vector_type(4))) float f32x4;

#if __has_builtin(__builtin_amdgcn_exp2f)
#define EXP2(x) __builtin_amdgcn_exp2f(x)
#else
#define EXP2(x) __expf((x) * 0.6931471805599453f)
#endif

static __device__ __forceinline__ short f2bf(float x) {
    __hip_bfloat16 b = __float2bfloat16(x);
    return *reinterpret_cast<short*>(&b);
}

// ---------------- Kernel 1: q/k/v projections ----------------
// Inner loop reads x via broadcast ds_read_b128 (2 per k) instead of 8 scalar
// b32 broadcasts: ~2x less LDS-pipe issue (proj was LDS-issue-bound).
#define PPT 16
__global__ void __launch_bounds__(256) proj_kernel(
        const float* __restrict__ xq, const float* __restrict__ xk,
        const float* __restrict__ xv,
        const float* __restrict__ wq, const float* __restrict__ bq,
        const float* __restrict__ wk, const float* __restrict__ bk,
        const float* __restrict__ wv, const float* __restrict__ bv,
        short* __restrict__ qbf,
        float* __restrict__ kbuf, short* __restrict__ kbf,
        float* __restrict__ vbuf, short* __restrict__ vbfT) {
    __shared__ float xs[CCH * PPT];          // xs[in*16 + p]
    const int n0 = blockIdx.x * PPT;
    const int t  = threadIdx.x;              // 0..255
    const int c  = t & 127;
    const int ph = t >> 7;                   // px half (wave-uniform)
    const int which = blockIdx.y;
    const float* x = (which == 0) ? xq : (which == 1) ? xk : xv;
    const float* w = (which == 0) ? wq : (which == 1) ? wk : wv;
    const float* b = (which == 0) ? bq : (which == 1) ? bk : bv;

#pragma unroll
    for (int it = 0; it < 8; ++it) {
        const int flat = it * 256 + t;       // 0..2047
        const int cc = flat >> 4;
        const int p  = flat & 15;
        xs[flat] = x[cc * NPIX + n0 + p];
    }
    __syncthreads();

    float acc[8];
    const float bb = b[c];
#pragma unroll
    for (int p = 0; p < 8; ++p) acc[p] = bb;

#pragma unroll 4
    for (int in = 0; in < CCH; ++in) {
        const float wv_ = w[in * CCH + c];
        const float4 xa = *(const float4*)(xs + in * PPT + ph * 8);
        const float4 xb = *(const float4*)(xs + in * PPT + ph * 8 + 4);
        acc[0] = fmaf(xa.x, wv_, acc[0]); acc[1] = fmaf(xa.y, wv_, acc[1]);
        acc[2] = fmaf(xa.z, wv_, acc[2]); acc[3] = fmaf(xa.w, wv_, acc[3]);
        acc[4] = fmaf(xb.x, wv_, acc[4]); acc[5] = fmaf(xb.y, wv_, acc[5]);
        acc[6] = fmaf(xb.z, wv_, acc[6]); acc[7] = fmaf(xb.w, wv_, acc[7]);
    }

    const int nb = n0 + ph * 8;
    if (which == 0) {
#pragma unroll
        for (int p = 0; p < 8; ++p)
            qbf[(size_t)(nb + p) * CCH + c] = f2bf(acc[p] * QSCALE);
    } else if (which == 1) {
#pragma unroll
        for (int p = 0; p < 8; ++p) {
            kbuf[(size_t)(nb + p) * CCH + c] = acc[p];
            kbf [(size_t)(nb + p) * CCH + c] = f2bf(acc[p]);
        }
    } else {
#pragma unroll
        for (int p = 0; p < 8; ++p) vbuf[(size_t)(nb + p) * CCH + c] = acc[p];
        short8 s0;
#pragma unroll
        for (int p = 0; p < 8; ++p) s0[p] = f2bf(acc[p]);
        *(short8*)(vbfT + (size_t)c * NPIX + nb) = s0;
    }
}

// ---------------- Kernel 2a: per-block cluster partial sums (72 blocks x 32 px) ----------------
__global__ void centersA_kernel(const float* __restrict__ kbuf, const int* __restrict__ labels,
                                float* __restrict__ cpart, float* __restrict__ denpart) {
    __shared__ float ls[2 * NCL * CCH];
    __shared__ int   lab_s[32];
    __shared__ float dps[2 * NCL];
    const int b = blockIdx.x;                // 0..71
    const int t = threadIdx.x;
    const int g = t >> 7, c = t & 127;
    if (t < 32) lab_s[t] = labels[b * 32 + t];
    for (int u = t; u < 2 * NCL * CCH; u += 256) ls[u] = 0.f;
    __syncthreads();

    const int n0 = b * 32 + g * 16;
    for (int p = 0; p < 16; ++p) {
        const int lab = lab_s[g * 16 + p];
        ls[(g * NCL + lab) * CCH + c] += kbuf[(size_t)(n0 + p) * CCH + c];
    }
    if (t < 2 * NCL) {
        const int g2 = t >> 4, cl = t & 15;
        int cnt = 0;
        for (int p = 0; p < 16; ++p) cnt += (lab_s[g2 * 16 + p] == cl) ? 1 : 0;
        dps[t] = (float)cnt;
    }
    __syncthreads();
    for (int u = t; u < NCL * CCH; u += 256)
        cpart[(size_t)b * NCL * CCH + u] = ls[u] + ls[NCL * CCH + u];
    if (t < NCL) denpart[b * NCL + t] = dps[t] + dps[NCL + t];
}

// ---------------- Kernel 2b: reduce partials -> bf16 centers ----------------
__global__ void centersB_kernel(const float* __restrict__ cpart, const float* __restrict__ denpart,
                                short* __restrict__ cbf) {
    const int idx = blockIdx.x * 256 + threadIdx.x;   // 0..2047
    const int kk  = idx >> 7;
    float den = 0.f;
    for (int b = 0; b < NBLK; ++b) den += denpart[b * NCL + kk];
    float s = 0.f;
    for (int b = 0; b < NBLK; ++b) s += cpart[(size_t)b * NCL * CCH + idx];
    cbf[idx] = f2bf(s / (den + 1e-6f));
}

// ---------------- Kernel 3: MFMA attention, barrier-free ----------------
// K/V (1.2 MB bf16 total) are L2-resident and each wave consumes only its own
// head's 64B slice of every row -> per-lane direct fragment loads have EXACTLY
// the same global traffic as the old cooperative LDS staging, minus 4 ds_writes
// + 2 __syncthreads per step. All remaining LDS (Pl, aclT) is wave-private, so
// the main loop has ZERO barriers; depth-1 register ping-pong hides L2 latency.
// aclT is stored [center][row] so the per-step center-score fetch is one
// ds_read_b128 per K-half instead of 4 ds_read_b32.
__global__ void __launch_bounds__(256, 4) attn_part_kernel(
        const short* __restrict__ qbf,  const short* __restrict__ kbf,
        const short* __restrict__ vbfT, const short* __restrict__ cbf,
        const int* __restrict__ labels, const float* __restrict__ pc,
        float* __restrict__ part_o, float* __restrict__ part_l) {
    __shared__ __align__(16) short Pl[NH][16 * 40];    // per-wave P tile
    __shared__ __align__(16) float aclT[NH][16][16];   // [center][q-row], wave-private
    __shared__ int   labl[KEYS];
    const int qt   = blockIdx.x;
    const int ks   = blockIdx.y;
    const int tid  = threadIdx.x;
    const int w    = tid >> 6;
    const int lane = tid & 63;
    const int quad = lane >> 4;
    const int lq   = lane & 15;
    const int i0   = qt * 16;
    const int j0   = ks * KEYS;

    for (int u = tid; u < KEYS / 4; u += 256)
        *(int4*)(labl + u * 4) = *(const int4*)(labels + j0 + u * 4);

    // loop-invariant Q A-frag (pre-scaled by log2e/sqrt(d) in proj)
    const short8 aq = *(const short8*)(qbf + (size_t)(i0 + lq) * CCH + w * HC + quad * 8);

    // center scores via one MFMA -> aclT transposed (wave-private, no barrier)
    {
        const short8 bc = *(const short8*)(cbf + (size_t)lq * CCH + w * HC + quad * 8);
        f32x4 z = {0.f, 0.f, 0.f, 0.f};
        f32x4 acd = __builtin_amdgcn_mfma_f32_16x16x32_bf16(aq, bc, z, 0, 0, 0);
        // lane (quad,lq) holds rows quad*4+r for center lq -> aclT[lq][quad*4+r]
        *(f32x4*)(&aclT[w][lq][quad * 4]) = acd;
    }
    int labi[4];
#pragma unroll
    for (int r = 0; r < 4; ++r) labi[r] = labels[i0 + quad * 4 + r];

    __syncthreads();   // only for labl (aclT/Pl are wave-private)

    // per-lane fragment base pointers
    const short* kp  = kbf  + (size_t)(j0 + lq) * CCH + w * HC + quad * 8;
    const short* vp  = vbfT + (size_t)(w * HC + lq) * NPIX + j0 + quad * 8;
    const float* pcp = pc   + (size_t)(i0 + quad * 4) * NPIX + j0 + lq;

    short8 k0A, k1A, v0A, v1A, k0B, k1B, v0B, v1B;
    float pcA[8], pcB[8];
    f32x4 accO0 = {0.f, 0.f, 0.f, 0.f};
    f32x4 accO1 = {0.f, 0.f, 0.f, 0.f};
    float lp[4] = {0.f, 0.f, 0.f, 0.f};

#define ISSUE(K0_, K1_, V0_, V1_, s) do {                                         \
        K0_ = *(const short8*)(kp + (size_t)(s) * 32 * CCH);                      \
        K1_ = *(const short8*)(kp + (size_t)((s) * 32 + 16) * CCH);               \
        V0_ = *(const short8*)(vp + (s) * 32);                                    \
        V1_ = *(const short8*)(vp + (size_t)16 * NPIX + (s) * 32);                \
    } while (0)

#define ISSUE_PC(dst, s) do {                                                     \
        _Pragma("unroll")                                                         \
        for (int r_ = 0; r_ < 4; ++r_) {                                          \
            dst[r_ * 2 + 0] = pcp[(size_t)r_ * NPIX + (s) * 32];                  \
            dst[r_ * 2 + 1] = pcp[(size_t)r_ * NPIX + (s) * 32 + 16];             \
        }                                                                         \
    } while (0)

#define COMPUTE(s, K0_, K1_, V0_, V1_, PCUSE) do {                                \
        _Pragma("unroll")                                                         \
        for (int kh = 0; kh < 2; ++kh) {                                          \
            const short8 bk = (kh == 0) ? K0_ : K1_;                              \
            f32x4 z = {0.f, 0.f, 0.f, 0.f};                                       \
            const f32x4 sv = __builtin_amdgcn_mfma_f32_16x16x32_bf16(aq, bk, z, 0, 0, 0);\
            const int slab = labl[(s) * 32 + kh * 16 + lq];                       \
            const f32x4 av4 = *(const f32x4*)(&aclT[w][slab][quad * 4]);          \
            _Pragma("unroll")                                                     \
            for (int r = 0; r < 4; ++r) {                                         \
                const float sc_ = (slab == labi[r]) ? sv[r] : av4[r] * PCUSE[r * 2 + kh];\
                const float p   = EXP2(sc_);                                      \
                lp[r] += p;                                                       \
                Pl[w][(quad * 4 + r) * 40 + kh * 16 + lq] = f2bf(p);              \
            }                                                                     \
        }                                                                         \
        const short8 ap = *(const short8*)(&Pl[w][lq * 40 + quad * 8]);           \
        accO0 = __builtin_amdgcn_mfma_f32_16x16x32_bf16(ap, V0_, accO0, 0, 0, 0); \
        accO1 = __builtin_amdgcn_mfma_f32_16x16x32_bf16(ap, V1_, accO1, 0, 0, 0); \
    } while (0)

    // prologue: step 0 K/V + pc into regs
    ISSUE(k0A, k1A, v0A, v1A, 0);
    ISSUE_PC(pcA, 0);

    for (int sb = 0; sb < NSTEP; sb += 2) {
        if (sb + 1 < NSTEP) { ISSUE(k0B, k1B, v0B, v1B, sb + 1); ISSUE_PC(pcB, sb + 1); }
        COMPUTE(sb, k0A, k1A, v0A, v1A, pcA);
        if (sb + 1 < NSTEP) {
            if (sb + 2 < NSTEP) { ISSUE(k0A, k1A, v0A, v1A, sb + 2); ISSUE_PC(pcA, sb + 2); }
            COMPUTE(sb + 1, k0B, k1B, v0B, v1B, pcB);
        }
    }
#undef ISSUE
#undef ISSUE_PC
#undef COMPUTE

#pragma unroll
    for (int r = 0; r < 4; ++r) {
        float v = lp[r];
        v += __shfl_xor(v, 1, 64);
        v += __shfl_xor(v, 2, 64);
        v += __shfl_xor(v, 4, 64);
        v += __shfl_xor(v, 8, 64);
        lp[r] = v;
    }
    if (lq == 0) {
#pragma unroll
        for (int r = 0; r < 4; ++r)
            part_l[((size_t)ks * NPIX + i0 + quad * 4 + r) * NH + w] = lp[r];
    }
#pragma unroll
    for (int r = 0; r < 4; ++r) {
        float* po = part_o + ((size_t)ks * NPIX + i0 + quad * 4 + r) * CCH + w * HC;
        po[lq]      = accO0[r];
        po[16 + lq] = accO1[r];
    }
}

// ---------------- Kernel 4: MLP hidden layer ----------------
__global__ void __launch_bounds__(256) mlp_h_kernel(
        const float* __restrict__ part_o, const float* __restrict__ part_l,
        const float* __restrict__ rs1,
        const float* __restrict__ wa, const float* __restrict__ ba,
        float* __restrict__ hout, int mode) {
    __shared__ float xs[16 * CCH];           // 8 KB
    const int n0 = blockIdx.x * 16;
    const int t  = threadIdx.x;

    if (mode == 0) {
        for (int u = t; u < 512; u += 256) {
            const int p = u >> 5, c4 = (u & 31) * 4;
            const int hh = c4 >> 5;
            float ls = 0.f;
#pragma unroll
            for (int ks = 0; ks < KSPLIT; ++ks)
                ls += part_l[((size_t)ks * NPIX + n0 + p) * NH + hh];
            float sx = 0.f, sy = 0.f, sz = 0.f, sw = 0.f;
#pragma unroll
            for (int ks = 0; ks < KSPLIT; ++ks) {
                const float4 v = *(const float4*)(part_o + ((size_t)ks * NPIX + n0 + p) * CCH + c4);
                sx += v.x; sy += v.y; sz += v.z; sw += v.w;
            }
            const float inv = 1.f / ls;
            xs[p * CCH + c4 + 0] = sx * inv;
            xs[p * CCH + c4 + 1] = sy * inv;
            xs[p * CCH + c4 + 2] = sz * inv;
            xs[p * CCH + c4 + 3] = sw * inv;
        }
    } else {
        for (int u = t; u < 512; u += 256) {
            const int p = u >> 5, c4 = (u & 31) * 4;
            *(float4*)(xs + p * CCH + c4) = *(const float4*)(rs1 + (size_t)(n0 + p) * CCH + c4);
        }
    }
    __syncthreads();

    const int hh = blockIdx.y * 64 + (t & 63);
    const int pg = t >> 6;                   // wave-uniform px group
    float acc[4];
    const float bb = ba[hh];
#pragma unroll
    for (int p = 0; p < 4; ++p) acc[p] = bb;

    for (int it = 0; it < CCH / 8; ++it) {
        float wr[8];
#pragma unroll
        for (int k = 0; k < 8; ++k) wr[k] = wa[(it * 8 + k) * 2 * CCH + hh];
#pragma unroll
        for (int p = 0; p < 4; ++p) {
            const float4 xa = *(const float4*)(xs + (pg * 4 + p) * CCH + it * 8);
            const float4 xb = *(const float4*)(xs + (pg * 4 + p) * CCH + it * 8 + 4);
            acc[p] = fmaf(xa.x, wr[0], acc[p]); acc[p] = fmaf(xa.y, wr[1], acc[p]);
            acc[p] = fmaf(xa.z, wr[2], acc[p]); acc[p] = fmaf(xa.w, wr[3], acc[p]);
            acc[p] = fmaf(xb.x, wr[4], acc[p]); acc[p] = fmaf(xb.y, wr[5], acc[p]);
            acc[p] = fmaf(xb.z, wr[6], acc[p]); acc[p] = fmaf(xb.w, wr[7], acc[p]);
        }
    }
#pragma unroll
    for (int p = 0; p < 4; ++p) {
        const float v = acc[p];
        hout[(size_t)(n0 + pg * 4 + p) * 2 * CCH + hh] = (v > 0.f) ? v : 0.01f * v;
    }
}

// ---------------- Kernel 5: MLP output layer + residual ----------------
__global__ void __launch_bounds__(256) mlp_o_kernel(
        const float* __restrict__ hin, const float* __restrict__ res,
        const float* __restrict__ wb, const float* __restrict__ bbp,
        float* __restrict__ outp, int mode) {
    __shared__ float hs[8 * 2 * CCH];        // 8 KB
    const int n0 = blockIdx.x * 8;
    const int t  = threadIdx.x;

    for (int u = t; u < 512; u += 256) {
        const int p = u >> 6, c4 = (u & 63) * 4;
        *(float4*)(hs + p * 2 * CCH + c4) = *(const float4*)(hin + (size_t)(n0 + p) * 2 * CCH + c4);
    }
    __syncthreads();

    const int c  = blockIdx.y * 64 + (t & 63);
    const int pg = t >> 6;                   // wave-uniform px group (2 px)
    const float bb = bbp[c];
    float a0 = bb, a1 = bb;

    for (int it = 0; it < 2 * CCH / 8; ++it) {
        float wr[8];
#pragma unroll
        for (int k = 0; k < 8; ++k) wr[k] = wb[(it * 8 + k) * CCH + c];
        const float4 ha = *(const float4*)(hs + (pg * 2 + 0) * 2 * CCH + it * 8);
        const float4 hb = *(const float4*)(hs + (pg * 2 + 0) * 2 * CCH + it * 8 + 4);
        a0 = fmaf(ha.x, wr[0], a0); a0 = fmaf(ha.y, wr[1], a0);
        a0 = fmaf(ha.z, wr[2], a0); a0 = fmaf(ha.w, wr[3], a0);
        a0 = fmaf(hb.x, wr[4], a0); a0 = fmaf(hb.y, wr[5], a0);
        a0 = fmaf(hb.z, wr[6], a0); a0 = fmaf(hb.w, wr[7], a0);
        const float4 hc = *(const float4*)(hs + (pg * 2 + 1) * 2 * CCH + it * 8);
        const float4 hd = *(const float4*)(hs + (pg * 2 + 1) * 2 * CCH + it * 8 + 4);
        a1 = fmaf(hc.x, wr[0], a1); a1 = fmaf(hc.y, wr[1], a1);
        a1 = fmaf(hc.z, wr[2], a1); a1 = fmaf(hc.w, wr[3], a1);
        a1 = fmaf(hd.x, wr[4], a1); a1 = fmaf(hd.y, wr[5], a1);
        a1 = fmaf(hd.z, wr[6], a1); a1 = fmaf(hd.w, wr[7], a1);
    }

    const int na = n0 + pg * 2, nb = na + 1;
    if (mode == 0) {
        outp[(size_t)na * CCH + c] = res[(size_t)na * CCH + c] + a0;
        outp[(size_t)nb * CCH + c] = res[(size_t)nb * CCH + c] + a1;
    } else {
        outp[(size_t)c * NPIX + na] = res[(size_t)na * CCH + c] + a0;
        outp[(size_t)c * NPIX + nb] = res[(size_t)nb * CCH + c] + a1;
    }
}

extern "C" void kernel_launch(void* const* d_in, const int* in_sizes, int n_in,
                              void* d_out, int out_size, void* d_ws, size_t ws_size,
                              hipStream_t stream) {
    const float* q_img = (const float*)d_in[0];
    const float* k_img = (const float*)d_in[1];
    const float* v_img = (const float*)d_in[2];
    const float* pc    = (const float*)d_in[3];
    const int*   labels= (const int*)  d_in[4];
    const float* wq = (const float*)d_in[5];
    const float* bq = (const float*)d_in[6];
    const float* wk = (const float*)d_in[7];
    const float* bk = (const float*)d_in[8];
    const float* wv = (const float*)d_in[9];
    const float* bv = (const float*)d_in[10];
    const float* w1a = (const float*)d_in[11];
    const float* b1a = (const float*)d_in[12];
    const float* w1b = (const float*)d_in[13];
    const float* b1b = (const float*)d_in[14];
    const float* w2a = (const float*)d_in[15];
    const float* b2a = (const float*)d_in[16];
    const float* w2b = (const float*)d_in[17];
    const float* b2b = (const float*)d_in[18];

    float* fw = (float*)d_ws;
    float* kbuf    = fw;                                  // [N][128]
    float* vbuf    = kbuf + (size_t)NPIX * CCH;           // [N][128]
    float* cpart   = vbuf + (size_t)NPIX * CCH;           // [72][16][128]
    float* denpart = cpart + (size_t)NBLK * NCL * CCH;    // [72][16]
    float* part_o  = denpart + NBLK * NCL;                // [KS][N][128]
    float* part_l  = part_o + (size_t)KSPLIT * NPIX * CCH;// [KS][N][4]
    float* h1      = part_l + (size_t)KSPLIT * NPIX * NH; // [N][256]
    float* rs1     = h1 + (size_t)NPIX * 2 * CCH;         // [N][128]
    float* h2      = rs1 + (size_t)NPIX * CCH;            // [N][256]
    short* sw      = (short*)(h2 + (size_t)NPIX * 2 * CCH);
    short* qbf     = sw;                                  // [N][128] bf16
    short* kbf     = qbf + (size_t)NPIX * CCH;            // [N][128] bf16
    short* vbfT    = kbf + (size_t)NPIX * CCH;            // [128][N] bf16
    short* cbf     = vbfT + (size_t)NPIX * CCH;           // [16][128] bf16
    float* out     = (float*)d_out;

    proj_kernel<<<dim3(NPIX / PPT, 3), 256, 0, stream>>>(q_img, k_img, v_img,
                                                         wq, bq, wk, bk, wv, bv,
                                                         qbf, kbuf, kbf, vbuf, vbfT);
    centersA_kernel<<<NBLK, 256, 0, stream>>>(kbuf, labels, cpart, denpart);
    centersB_kernel<<<NCL * CCH / 256, 256, 0, stream>>>(cpart, denpart, cbf);
    attn_part_kernel<<<dim3(NPIX / 16, KSPLIT), 256, 0, stream>>>(qbf, kbf, vbfT, cbf,
                                                                  labels, pc, part_o, part_l);
    mlp_h_kernel<<<dim3(NPIX / 16, 4), 256, 0, stream>>>(part_o, part_l, nullptr,
                                                         w1a, b1a, h1, 0);
    mlp_o_kernel<<<dim3(NPIX / 8, 2), 256, 0, stream>>>(h1, vbuf, w1b, b1b, rs1, 0);
    mlp_h_kernel<<<dim3(NPIX / 16, 4), 256, 0, stream>>>(nullptr, nullptr, rs1,
                                                         w2a, b2a, h2, 1);
    mlp_o_kernel<<<dim3(NPIX / 8, 2), 256, 0, stream>>>(h2, rs1, w2b, b2b, out, 1);
}